// Round 1
// baseline (934.672 us; speedup 1.0000x reference)
//
#include <hip/hip_runtime.h>
#include <hip/hip_bf16.h>
#include <math.h>

// Problem constants
#define BATCH 64
#define TSEQ  512
#define BT    (BATCH*TSEQ)      // 32768
#define EDIM  300
#define HID   128
#define G4    512               // 4*H
#define KTAG  3

// ---------------------------------------------------------------------------
// Kernel A: fused embedding gather + input GEMM for both directions.
// Computes xW[dir][m][j] = emb[tokens[m]] @ W{f,b} + b{f,b}
// M = 32768 rows, N = 1024 cols (dir*512 + j), K = 300.
// 64x64 tile, 256 threads, 4x4 micro-tile, f32 FMA.
// ---------------------------------------------------------------------------
__global__ __launch_bounds__(256) void embed_gemm(
    const int* __restrict__ tokens, const float* __restrict__ emb,
    const float* __restrict__ Wf, const float* __restrict__ bf,
    const float* __restrict__ Wb, const float* __restrict__ bb,
    float* __restrict__ xW)
{
    const int c0 = blockIdx.x * 64;   // 0..960
    const int m0 = blockIdx.y * 64;   // 0..32704
    const int tid = threadIdx.x;

    __shared__ float As[16][68];      // [k][row], pad 68 for bank spread + 16B align
    __shared__ float Bs[16][68];      // [k][col]
    __shared__ int   toks[64];

    if (tid < 64) toks[tid] = tokens[m0 + tid];
    __syncthreads();

    const int dir = c0 >> 9;          // entire 64-col tile in one direction
    const float* __restrict__ W    = dir ? Wb : Wf;
    const float* __restrict__ bias = dir ? bb : bf;
    const int j0 = c0 & 511;

    const int tx = tid & 15;          // col group (4 cols)
    const int ty = tid >> 4;          // row group (4 rows)

    float acc[4][4] = {};

    for (int k0 = 0; k0 < EDIM; k0 += 16) {
        // A load: kk = tid&15 (consecutive k per 16 threads -> coalesced 64B)
        {
            const int kk = tid & 15, i0 = tid >> 4;
            const int k = k0 + kk;
            #pragma unroll
            for (int r = 0; r < 4; ++r) {
                const int i = i0 + r * 16;
                As[kk][i] = (k < EDIM) ? emb[(size_t)toks[i] * EDIM + k] : 0.f;
            }
        }
        // B load: cc = tid&63 consecutive cols -> coalesced 256B
        {
            const int cc = tid & 63, kb = tid >> 6;
            #pragma unroll
            for (int r = 0; r < 4; ++r) {
                const int kk = kb + r * 4;
                const int k = k0 + kk;
                Bs[kk][cc] = (k < EDIM) ? W[(size_t)k * G4 + j0 + cc] : 0.f;
            }
        }
        __syncthreads();
        #pragma unroll
        for (int kk = 0; kk < 16; ++kk) {
            const float4 a = *(const float4*)&As[kk][ty * 4];
            const float4 b = *(const float4*)&Bs[kk][tx * 4];
            const float av[4] = {a.x, a.y, a.z, a.w};
            const float bv[4] = {b.x, b.y, b.z, b.w};
            #pragma unroll
            for (int i = 0; i < 4; ++i)
                #pragma unroll
                for (int j = 0; j < 4; ++j)
                    acc[i][j] += av[i] * bv[j];
        }
        __syncthreads();
    }

    // epilogue: +bias, float4 stores (coalesced within a wave)
    const float4 b4 = *(const float4*)&bias[j0 + tx * 4];
    const size_t obase = (size_t)dir * BT * G4;
    #pragma unroll
    for (int i = 0; i < 4; ++i) {
        const int m = m0 + ty * 4 + i;
        float4 v;
        v.x = acc[i][0] + b4.x;
        v.y = acc[i][1] + b4.y;
        v.z = acc[i][2] + b4.z;
        v.w = acc[i][3] + b4.w;
        *(float4*)&xW[obase + (size_t)m * G4 + j0 + tx * 4] = v;
    }
}

// ---------------------------------------------------------------------------
// Kernel B: LSTM recurrence, one block per (dir, batch) = 128 blocks.
// 512 threads; thread j owns U[:,j] in 128 VGPRs. h broadcast via LDS.
// dir=1 walks t backwards; h stored at ORIGINAL time index so no reversal
// is needed downstream.
// ---------------------------------------------------------------------------
__global__ __launch_bounds__(512) void lstm_kernel(
    const float* __restrict__ Uf, const float* __restrict__ Ub,
    const float* __restrict__ xW, float* __restrict__ hs)
{
    const int blk = blockIdx.x;       // 0..127
    const int dir = blk >> 6;
    const int j   = threadIdx.x;      // 0..511
    const float* __restrict__ U = dir ? Ub : Uf;

    float u[128];
    #pragma unroll
    for (int k = 0; k < 128; ++k) u[k] = U[k * G4 + j];   // coalesced per k

    __shared__ float h_lds[HID];
    __shared__ float z_lds[G4];
    if (j < HID) h_lds[j] = 0.f;
    float c = 0.f;

    const float* __restrict__ xW_blk = xW + (size_t)blk * (TSEQ * G4);
    float* __restrict__ hs_blk = hs + (size_t)blk * (TSEQ * HID);
    __syncthreads();

    int tt = dir ? (TSEQ - 1) : 0;
    const int tstep = dir ? -1 : 1;
    float xw_cur = xW_blk[(size_t)tt * G4 + j];

    for (int t = 0; t < TSEQ; ++t) {
        const int ttn = tt + tstep;
        // prefetch next step's xW early (address independent of this step)
        float xw_next = 0.f;
        if (t < TSEQ - 1) xw_next = xW_blk[(size_t)ttn * G4 + j];

        float acc = 0.f;
        #pragma unroll
        for (int k = 0; k < 128; k += 4) {
            const float4 hv = *(const float4*)&h_lds[k];   // broadcast reads
            acc += hv.x * u[k] + hv.y * u[k + 1] + hv.z * u[k + 2] + hv.w * u[k + 3];
        }
        z_lds[j] = xw_cur + acc;
        __syncthreads();

        if (j < HID) {
            const float zi = z_lds[j];
            const float zf = z_lds[j + HID];
            const float zg = z_lds[j + 2 * HID];
            const float zo = z_lds[j + 3 * HID];
            const float ig = 1.f / (1.f + expf(-zi));
            const float fg = 1.f / (1.f + expf(-zf));
            const float gg = tanhf(zg);
            const float og = 1.f / (1.f + expf(-zo));
            c = fg * c + ig * gg;
            const float h = og * tanhf(c);
            h_lds[j] = h;
            hs_blk[(size_t)tt * HID + j] = h;
        }
        __syncthreads();
        xw_cur = xw_next;
        tt = ttn;
    }
}

// ---------------------------------------------------------------------------
// Kernel C: fold dense + CRF inner kernel: Wd2 = Wd @ crf_W, b2 = bd@crf_W+crf_b
// ---------------------------------------------------------------------------
__global__ void prep_kernel(const float* __restrict__ Wd, const float* __restrict__ bd,
                            const float* __restrict__ crf_W, const float* __restrict__ crf_b,
                            float* __restrict__ Wd2, float* __restrict__ b2)
{
    const int u = threadIdx.x;        // 256 threads
    #pragma unroll
    for (int k = 0; k < KTAG; ++k) {
        float s = 0.f;
        #pragma unroll
        for (int j = 0; j < KTAG; ++j) s += Wd[u * KTAG + j] * crf_W[j * KTAG + k];
        Wd2[u * KTAG + k] = s;
    }
    if (u < KTAG) {
        float s = crf_b[u];
        #pragma unroll
        for (int j = 0; j < KTAG; ++j) s += bd[j] * crf_W[j * KTAG + u];
        b2[u] = s;
    }
}

// ---------------------------------------------------------------------------
// Kernel D: potentials. One wave per (b,t): pot = [h_f|h_b] @ Wd2 + b2 (+bounds)
// ---------------------------------------------------------------------------
__global__ __launch_bounds__(256) void pot_kernel(
    const float* __restrict__ hs, const float* __restrict__ Wd2,
    const float* __restrict__ b2, const float* __restrict__ left_b,
    const float* __restrict__ right_b, float* __restrict__ pot)
{
    const int wave = blockIdx.x * 4 + (threadIdx.x >> 6);  // (b,t) index
    const int lane = threadIdx.x & 63;
    const int b = wave >> 9, t = wave & 511;

    const float* __restrict__ hf = hs + ((size_t)b * TSEQ + t) * HID;
    const float* __restrict__ hb = hf + (size_t)BATCH * TSEQ * HID;

    const float x0 = hf[lane], x1 = hf[lane + 64];
    const float x2 = hb[lane], x3 = hb[lane + 64];

    float a[KTAG];
    #pragma unroll
    for (int k = 0; k < KTAG; ++k)
        a[k] = x0 * Wd2[lane * KTAG + k] + x1 * Wd2[(lane + 64) * KTAG + k]
             + x2 * Wd2[(lane + 128) * KTAG + k] + x3 * Wd2[(lane + 192) * KTAG + k];

    #pragma unroll
    for (int off = 32; off; off >>= 1) {
        a[0] += __shfl_xor(a[0], off);
        a[1] += __shfl_xor(a[1], off);
        a[2] += __shfl_xor(a[2], off);
    }

    if (lane < KTAG) {
        float v = a[lane] + b2[lane];
        if (t == 0)        v += left_b[lane];
        if (t == TSEQ - 1) v += right_b[lane];
        pot[(size_t)wave * KTAG + lane] = v;
    }
}

// ---------------------------------------------------------------------------
// Kernel E: Viterbi decode, one block per batch. Exact first-max-wins argmax
// semantics (matches jnp.argmax). Backpointers packed 2 bits/state in LDS.
// Decoded tags written as float32.
// ---------------------------------------------------------------------------
__global__ __launch_bounds__(64) void viterbi_kernel(
    const float* __restrict__ pot, const float* __restrict__ chain,
    float* __restrict__ decoded)
{
    const int b = blockIdx.x;
    const int lane = threadIdx.x;

    __shared__ float p[TSEQ][KTAG];
    __shared__ int bp[TSEQ - 1];
    __shared__ unsigned char tags[TSEQ];

    const float* __restrict__ pb = pot + (size_t)b * TSEQ * KTAG;
    for (int i = lane; i < TSEQ * KTAG; i += 64) ((float*)p)[i] = pb[i];
    __syncthreads();

    if (lane == 0) {
        float tr[KTAG][KTAG];
        #pragma unroll
        for (int i = 0; i < 9; ++i) tr[i / 3][i % 3] = chain[i];

        float a0 = p[0][0], a1 = p[0][1], a2 = p[0][2];
        for (int t = 1; t < TSEQ; ++t) {
            float n[KTAG]; int bpk[KTAG];
            #pragma unroll
            for (int kn = 0; kn < KTAG; ++kn) {
                const float s0 = a0 + tr[0][kn];
                const float s1 = a1 + tr[1][kn];
                const float s2 = a2 + tr[2][kn];
                float best = s0; int arg = 0;
                if (s1 > best) { best = s1; arg = 1; }
                if (s2 > best) { best = s2; arg = 2; }
                n[kn] = best + p[t][kn];
                bpk[kn] = arg;
            }
            bp[t - 1] = bpk[0] | (bpk[1] << 2) | (bpk[2] << 4);
            a0 = n[0]; a1 = n[1]; a2 = n[2];
        }
        int tag = 0; float best = a0;
        if (a1 > best) { best = a1; tag = 1; }
        if (a2 > best) { best = a2; tag = 2; }
        tags[TSEQ - 1] = (unsigned char)tag;
        for (int t = TSEQ - 2; t >= 0; --t) {
            tag = (bp[t] >> (2 * tag)) & 3;
            tags[t] = (unsigned char)tag;
        }
    }
    __syncthreads();
    for (int t = lane; t < TSEQ; t += 64)
        decoded[(size_t)b * TSEQ + t] = (float)tags[t];
}

// ---------------------------------------------------------------------------
extern "C" void kernel_launch(void* const* d_in, const int* in_sizes, int n_in,
                              void* d_out, int out_size, void* d_ws, size_t ws_size,
                              hipStream_t stream) {
    const int*   tokens  = (const int*)d_in[0];
    const float* emb     = (const float*)d_in[1];
    const float* Wf      = (const float*)d_in[2];
    const float* Uf      = (const float*)d_in[3];
    const float* bf      = (const float*)d_in[4];
    const float* Wb      = (const float*)d_in[5];
    const float* Ub      = (const float*)d_in[6];
    const float* bb      = (const float*)d_in[7];
    const float* Wd      = (const float*)d_in[8];
    const float* bd      = (const float*)d_in[9];
    const float* crf_W   = (const float*)d_in[10];
    const float* crf_b   = (const float*)d_in[11];
    const float* chain   = (const float*)d_in[12];
    const float* left_b  = (const float*)d_in[13];
    const float* right_b = (const float*)d_in[14];

    float* out = (float*)d_out;                    // [0,32768): decoded, then pot
    float* pot = out + BT;

    float* xW  = (float*)d_ws;                     // 2 * 32768 * 512 f32 = 128 MB
    float* hs  = xW + (size_t)2 * BT * G4;         // 2 * 64 * 512 * 128 f32 = 32 MB
    float* Wd2 = hs + (size_t)2 * BATCH * TSEQ * HID;
    float* b2  = Wd2 + 2 * HID * KTAG;

    dim3 gA(1024 / 64, BT / 64);                   // 16 x 512 blocks
    embed_gemm<<<gA, 256, 0, stream>>>(tokens, emb, Wf, bf, Wb, bb, xW);
    prep_kernel<<<1, 256, 0, stream>>>(Wd, bd, crf_W, crf_b, Wd2, b2);
    lstm_kernel<<<128, 512, 0, stream>>>(Uf, Ub, xW, hs);
    pot_kernel<<<BT / 4, 256, 0, stream>>>(hs, Wd2, b2, left_b, right_b, pot);
    viterbi_kernel<<<BATCH, 64, 0, stream>>>(pot, chain, out);
}